// Round 10
// baseline (226.655 us; speedup 1.0000x reference)
//
#include <hip/hip_runtime.h>
#include <stdint.h>

// Problem constants: B=8, P=4096, N=1024, H=W=1024, labels 0..1024
#define PPTS 4096
#define NGT  1024
#define HH   1024
#define WW   1024
#define EVPOOL_CAP 2047   // LDS event-slot pool; totEv ~1950 (spill -> global ws)
#define BGCAP 160         // max bg steps (E[m] ~65)

// workspace layout (per batch): hist = 3136 ints (bucket[1025], occ[1025],
// fMax[1025], present u32[33]); labels u16[4096]; spill u16[2048]; gbm u32[128]
#define HIST_I32   3136
#define HIST_BYTES (8 * HIST_I32 * 4)            // 100352
#define LAB_OFF    HIST_BYTES
#define SPILL_OFF  (LAB_OFF + 8 * PPTS * 2)      // 165888
#define SPILL_CAP  2048
#define GBM_OFF    (SPILL_OFF + 8 * SPILL_CAP * 2)  // 198656
#define WS_NEED    (GBM_OFF + 8 * 512)

typedef unsigned long long u64;

__device__ __forceinline__ float pdist(float vx, float vy, float ux, float uy) {
    float dx = __fsub_rn(vx, ux);
    float dy = __fsub_rn(vy, uy);
    return __fsqrt_rn(__fadd_rn(__fmul_rn(dx, dx), __fmul_rn(dy, dy)));
}

// K1: 8 blocks per batch, 512 threads — labels (random mask gather) + global
// histograms + zero the fallback bitmap.
__global__ __launch_bounds__(512) void label_kernel(
    const float* __restrict__ pred, const int* __restrict__ keys,
    const int* __restrict__ masks, int* __restrict__ hist,
    unsigned short* __restrict__ labs, unsigned* __restrict__ gbm)
{
    const int blk = blockIdx.x, b = blk >> 3, sb = blk & 7;
    const int t = threadIdx.x;
    const int p = (sb << 9) + t;
    const float2* Ub2 = (const float2*)(pred + (size_t)b * PPTS * 2);
    const int* Mb = masks + (size_t)b * HH * WW;
    int* H = hist + (size_t)b * HIST_I32;

    float2 u = Ub2[p];
    int xi = (int)rintf(__fmul_rn(u.x, 1024.0f));   // rintf == jnp.round (half-even)
    int yi = (int)rintf(__fmul_rn(u.y, 1024.0f));
    xi = min(max(xi, 0), HH - 1);
    yi = min(max(yi, 0), WW - 1);
    int lab = Mb[xi * WW + yi];
    labs[(size_t)b * PPTS + p] = (unsigned short)lab;
    atomicAdd(&H[lab], 1);
    if (sb < 2) {
        int j = (sb << 9) + t;
        int k1 = keys[(size_t)b * NGT + j] + 1;     // label of step j
        atomicAdd(&H[1025 + k1], 1);
        atomicMax(&H[2050 + k1], 1023 - j);         // firstOcc = 1023 - max
        atomicOr((unsigned*)&H[3075 + (k1 >> 5)], 1u << (k1 & 31));
    }
    if (sb == 7 && t < 128) gbm[b * 128 + t] = 0;   // fallback bitmap zero
}

// K2: one block per batch.
//  C   : quad-packed u64 exclusive scan (bg<<48|pr<<32|ev<<16|occ) -> bg-first
//        bucket starts, occ starts, per-step event offsets evAx.
//  D   : scatter coords+ids (bg0 list = [0,nBg0) for free), occ lists.
//  S1  : label-owner computes occurrence ranks (in-register sortnet <=16);
//        buckets>16 processed sequentially now; occ>16 flagged for S3.
//  S2  : ROUNDS — round r: thread j (V[j] in register!) does its label's
//        r-th occurrence argmin using consMask[l] (u16); round-0 winners emit
//        dump events at evAx[j].
//  S3  : rare occ>16 labels, exact sequential.
//  stg : event slots -> contiguous staged pool at [nBg0, nBg0+totEv).
//  beta: speculative per-step argmins, 5 steps per wave share one LDS stream.
//  2c  : O(1) dup-check (atomicOr presence) -> parallel commit (exact) or
//        sequential fallback walk (global bitmap, rare).
__global__ __launch_bounds__(1024) void matcher_kernel(
    const float* __restrict__ pred,    // [B,P,2]
    const float* __restrict__ coords,  // [B,N,2]
    const int*   __restrict__ keys,    // [B,N]
    const int*   __restrict__ masks,   // [B,H,W] (mono path only)
    float* __restrict__ out,           // [B*N src][B*N tgt][B total]
    const int* __restrict__ hist, const unsigned short* __restrict__ labs,
    unsigned short* __restrict__ spill, unsigned* __restrict__ gbmAll,
    int useWs, int B)
{
    __shared__ __align__(16) char regU[32768];   // bucketC f2[4096] (bg0 + staged ev)
    __shared__ __align__(8)  char regE[8192];    // ldsEnt u16[4096]
    __shared__ __align__(8)  char regB[8200];    // bEnd[1025]+occA[1025] -> specWin u64[BGCAP]
    __shared__ __align__(8)  char regP[6144];    // firstOcc -> consMask u16[1025]+evPool u16[2047]; vSteps
    __shared__ __align__(4)  char regS[336];     // present u32[33] -> bgListSh u16[BGCAP]
    __shared__ __align__(8)  char regT[2048];    // bSt u16[1024] -> dupBits u32[128]
    __shared__ u64            wScr64[16];
    __shared__ u64            sTot;
    __shared__ unsigned short evAx[1024];        // per-step exclusive event offsets
    __shared__ unsigned short occList[NGT];
    __shared__ short          matchU[NGT];
    __shared__ unsigned char  rankOf[NGT];       // 0xFE unassigned/slow, 0xFD done
    __shared__ int            scal[4];           // 0:bgCnt 1:maxR 2:dupFlag 3:slowFlag

    float2*         bucketC  = (float2*)regU;
    unsigned short* ldsEnt   = (unsigned short*)regE;
    int*            bEnd     = (int*)regB;
    int*            occA     = ((int*)regB) + 1025;
    u64*            specWin  = (u64*)regB;            // alias (post-S3)
    int*            firstOcc = (int*)regP;            // dead after C
    unsigned short* consMask = (unsigned short*)regP; // [0,2050)
    unsigned short* evPool   = (unsigned short*)(regP + 2050); // [2050,6144)
    float2*         vSteps   = (float2*)regP;         // [0,1280) post-rounds
    unsigned*       present  = (unsigned*)regS;
    unsigned short* bgListSh = (unsigned short*)regS;
    unsigned short* bSt      = (unsigned short*)regT;
    unsigned*       dupBits  = (unsigned*)regT;       // alias (post-beta)
    int*   wScrI = (int*)wScr64;
    float* wScrF = (float*)wScr64;

    const int b = blockIdx.x;
    const int t = threadIdx.x;
    const int lane = t & 63, wv = t >> 6;
    const float* Ub = pred   + (size_t)b * PPTS * 2;
    const float2* Ub2 = (const float2*)Ub;
    const float2* Vb2 = (const float2*)(coords + (size_t)b * NGT * 2);
    const int*   Kb = keys   + (size_t)b * NGT;
    unsigned short* evSpillB = spill + (size_t)b * SPILL_CAP;
    unsigned* gbm = gbmAll + (size_t)b * 128;
    const int spillCap = useWs ? SPILL_CAP : 0;

    // ---- A/B: init + labels & histograms (load from ws or build) ----
    if (t == 0) { scal[0] = 0; scal[1] = 0; scal[2] = 0; scal[3] = 0; }
    const int k1 = Kb[t] + 1;                    // label of step j=t, in [1,1024]
    const float2 vMe = Vb2[t];                   // V of my own step — register!
    int lab[4]; float2 up[4];
    #pragma unroll
    for (int i = 0; i < 4; i++) up[i] = Ub2[t + (i << 10)];
    if (useWs) {
        const int* H = hist + (size_t)b * HIST_I32;
        bEnd[t] = H[t]; occA[t] = H[1025 + t]; firstOcc[t] = 1023 - H[2050 + t];
        if (t == 0) { bEnd[1024] = H[1024]; occA[1024] = H[2049];
                      firstOcc[1024] = 1023 - H[3074]; }
        if (t < 33) present[t] = ((const unsigned*)H)[3075 + t];
        const unsigned short* Lb = labs + (size_t)b * PPTS;
        #pragma unroll
        for (int i = 0; i < 4; i++) lab[i] = Lb[t + (i << 10)];
    } else {
        bEnd[t] = 0; occA[t] = 0; firstOcc[t] = 0x7FFFFFFF;
        if (t == 0) { bEnd[1024] = 0; occA[1024] = 0; firstOcc[1024] = 0x7FFFFFFF; }
        if (t < 33) present[t] = 0;
        if (t < 128) gbm[t] = 0;                 // mono: zero fallback bitmap
        __syncthreads();
        const int* Mb = masks + (size_t)b * HH * WW;
        atomicOr(&present[k1 >> 5], 1u << (k1 & 31));
        atomicAdd(&occA[k1], 1);
        atomicMin(&firstOcc[k1], t);
        #pragma unroll
        for (int i = 0; i < 4; i++) {
            float2 u = up[i];
            int xi = (int)rintf(__fmul_rn(u.x, 1024.0f));
            int yi = (int)rintf(__fmul_rn(u.y, 1024.0f));
            xi = min(max(xi, 0), HH - 1);
            yi = min(max(yi, 0), WW - 1);
            lab[i] = Mb[xi * WW + yi];
            atomicAdd(&bEnd[lab[i]], 1);
        }
    }
    __syncthreads();

    // ---- C: quad-packed exclusive scan (bg<<48 | pr<<32 | ev<<16 | occ) ----
    {
        int c0 = bEnd[t], o0 = occA[t];
        bool pr0 = (present[t >> 5] >> (t & 31)) & 1u;
        int bCnt = bEnd[k1];
        int fo   = firstOcc[k1];
        int evc  = (fo == t && bCnt > 0) ? (bCnt - 1) : 0;
        u64 myv = (pr0 ? ((u64)(unsigned)c0 << 32) : ((u64)(unsigned)c0 << 48))
                  | ((u64)(unsigned)evc << 16) | (u64)(unsigned)o0;
        u64 add1 = 0; bool pr1 = false;
        if (t == 1023) {                          // fold label 1024 (no step 1024)
            int c1 = bEnd[1024], o1 = occA[1024];
            pr1 = present[32] & 1u;
            add1 = (pr1 ? ((u64)(unsigned)c1 << 32) : ((u64)(unsigned)c1 << 48))
                   | (u64)(unsigned)o1;
        }
        u64 tot = myv + add1;
        u64 inc = tot;
        #pragma unroll
        for (int off = 1; off < 64; off <<= 1) {
            u64 n = __shfl_up(inc, off, 64);
            if (lane >= off) inc += n;
        }
        if (lane == 63) wScr64[wv] = inc;
        __syncthreads();
        if (t < 16) {
            u64 v = wScr64[t], inc2 = v;
            #pragma unroll
            for (int off = 1; off < 16; off <<= 1) {
                u64 n = __shfl_up(inc2, off, 64);
                if (t >= off) inc2 += n;
            }
            wScr64[t] = inc2 - v;
            if (t == 15) sTot = inc2;
        }
        __syncthreads();
        u64 excl = wScr64[wv] + inc - tot;
        int nBg0v = (int)(sTot >> 48);
        int bgS = (int)(excl >> 48);
        int prS = (int)((excl >> 32) & 0xFFFF);
        int evS = (int)((excl >> 16) & 0xFFFF);
        int ocS = (int)(excl & 0xFFFF);
        int start0 = pr0 ? (nBg0v + prS) : bgS;
        bEnd[t] = start0;                         // scatter cursor (start)
        occA[t] = ocS;
        evAx[t] = (unsigned short)evS;
        if (t >= 1) bSt[t - 1] = (unsigned short)start0;  // start of label t
        if (t == 1023) {
            u64 ex1 = excl + myv;
            int bgS1 = (int)(ex1 >> 48);
            int prS1 = (int)((ex1 >> 32) & 0xFFFF);
            int start1 = pr1 ? (nBg0v + prS1) : bgS1;
            bEnd[1024] = start1; occA[1024] = (int)(ex1 & 0xFFFF);
            bSt[1023] = (unsigned short)start1;
        }
    }
    __syncthreads();
    const int nBg0  = (int)(sTot >> 48);
    const int totEv = (int)((sTot >> 16) & 0xFFFF);
    const int EVcap = min(EVPOOL_CAP, PPTS - nBg0);

    // ---- D: scatter coords+ids (bg labels land in [0,nBg0)), occ lists ----
    consMask[t] = 0;
    if (t == 0) consMask[1024] = 0;   // BUGFIX r9: label 1024 was never zeroed
    rankOf[t] = 0xFE;
    #pragma unroll
    for (int i = 0; i < 4; i++) {
        int p = t + (i << 10);
        int slot = atomicAdd(&bEnd[lab[i]], 1);
        ldsEnt[slot] = (unsigned short)p;
        bucketC[slot] = up[i];
    }
    {
        int slot = atomicAdd(&occA[k1], 1);
        occList[slot] = (unsigned short)t;
    }
    __syncthreads();

    // ---- S1: owner of label t+1 computes ranks (reg sortnet <=16) ----
    float costPartial = 0.0f;
    {
        const int os = occA[t], oe = occA[t + 1];
        const int occCnt = oe - os;
        const int bs = bSt[t], be = bEnd[t + 1];
        const int bn = be - bs;
        int vmax = 0;
        if (occCnt > 16) {
            scal[3] = 1;                          // S3 handles (rankOf stays 0xFE)
        } else if (occCnt > 0) {
            unsigned jreg[16];
            #pragma unroll
            for (int o = 0; o < 16; o++)
                jreg[o] = (o < occCnt) ? (unsigned)occList[os + o] : 0xFFFFu;
            #pragma unroll
            for (int rr = 0; rr < 16; rr++) {     // odd-even transposition sort
                #pragma unroll
                for (int i = (rr & 1); i + 1 < 16; i += 2) {
                    unsigned a = jreg[i], c = jreg[i + 1];
                    if (a > c) { jreg[i] = c; jreg[i + 1] = a; }
                }
            }
            if (bn > 16) {
                // rare: big bucket — full sequential chain now
                u64 cons = 0;
                #pragma unroll
                for (int o = 0; o < 16; o++) {
                    if (o < occCnt) {
                        int j = (int)jreg[o];
                        float2 v = Vb2[j];
                        u64 best = ~0ull;
                        for (int e = bs; e < be; e++) {
                            int eIdx = e - bs;
                            int p = ldsEnt[e];
                            bool consd;
                            if (eIdx < 64) consd = (cons >> eIdx) & 1ull;
                            else {                // exact fallback (bucket>64, ~never)
                                consd = false;
                                for (int o2 = 0; o2 < o; o2++)
                                    if ((int)matchU[jreg[o2]] == p) { consd = true; break; }
                            }
                            if (consd) continue;
                            float2 u = bucketC[e];
                            float d = pdist(v.x, v.y, u.x, u.y);
                            u64 pk = ((u64)__float_as_uint(d) << 24)
                                     | ((u64)(unsigned)p << 12)
                                     | (u64)(unsigned)eIdx;
                            if (pk < best) best = pk;
                        }
                        if (best != ~0ull) {
                            int eW = (int)(best & 0xFFFull);
                            matchU[j] = (short)((best >> 12) & 0xFFFull);
                            costPartial = __fadd_rn(costPartial,
                                __uint_as_float((unsigned)(best >> 24)));
                            if (eW < 64) cons |= 1ull << eW;
                            if (o == 0) {         // emit dump events
                                int base = evAx[j], w3 = 0;
                                for (int e = bs; e < be; e++) {
                                    if (e - bs == eW) continue;
                                    int idx = base + w3;
                                    if (idx < EVcap) evPool[idx] = (unsigned short)e;
                                    else if (idx - EVcap < spillCap)
                                        evSpillB[idx - EVcap] = ldsEnt[e];
                                    w3++;
                                }
                            }
                        } else matchU[j] = -2;
                        rankOf[j] = 0xFD;         // done
                    }
                }
            } else {
                #pragma unroll
                for (int o = 0; o < 16; o++)
                    if (o < occCnt) rankOf[jreg[o]] = (unsigned char)o;
                vmax = occCnt;
            }
        }
        // block-max of vmax -> scal[1]
        #pragma unroll
        for (int off = 32; off >= 1; off >>= 1)
            vmax = max(vmax, __shfl_xor(vmax, off, 64));
        if (lane == 0) wScrI[wv] = vmax;
    }
    __syncthreads();
    if (t < 16) {
        int v = wScrI[t];
        #pragma unroll
        for (int off = 8; off >= 1; off >>= 1) v = max(v, __shfl_xor(v, off, 64));
        if (t == 0) scal[1] = v;
    }
    __syncthreads();

    // ---- S2: rounds — thread j does its label's r-th occurrence ----
    {
        const int maxR = scal[1];
        const unsigned char myRank = rankOf[t];
        const int bs = bSt[k1 - 1], be = bEnd[k1];
        for (int r = 0; r < maxR; r++) {
            if (myRank == (unsigned char)r) {
                unsigned cm = consMask[k1];
                u64 best = ~0ull;
                for (int e = bs; e < be; e++) {
                    int eIdx = e - bs;
                    if ((cm >> eIdx) & 1u) continue;
                    float2 u = bucketC[e];
                    float d = pdist(vMe.x, vMe.y, u.x, u.y);
                    u64 pk = ((u64)__float_as_uint(d) << 24)
                             | ((u64)(unsigned)ldsEnt[e] << 12) | (u64)(unsigned)eIdx;
                    if (pk < best) best = pk;
                }
                if (best != ~0ull) {
                    int eW = (int)(best & 0xFFFull);
                    matchU[t] = (short)((best >> 12) & 0xFFFull);
                    costPartial = __fadd_rn(costPartial,
                                            __uint_as_float((unsigned)(best >> 24)));
                    consMask[k1] = (unsigned short)(cm | (1u << eW)); // unique writer
                    if (r == 0) {                 // first occurrence: emit dumps
                        int base = evAx[t], w3 = 0;
                        for (int e = bs; e < be; e++) {
                            if (e - bs == eW) continue;
                            int idx = base + w3;
                            if (idx < EVcap) evPool[idx] = (unsigned short)e;
                            else if (idx - EVcap < spillCap)
                                evSpillB[idx - EVcap] = ldsEnt[e];
                            w3++;
                        }
                    }
                } else matchU[t] = -2;
            }
            __syncthreads();
        }
    }

    // ---- S3: occ>16 labels (astronomically rare), exact sequential ----
    if (scal[3]) {
        const int os = occA[t], oe = occA[t + 1];
        const int occCnt = oe - os;
        if (occCnt > 16) {
            const int bs = bSt[t], be = bEnd[t + 1];
            u64 cons = 0;
            int prevJ = -1;
            for (int o = 0; o < occCnt; o++) {
                int j = 0x7FFFFFFF;               // selection: next smallest j
                for (int q = os; q < oe; q++) {
                    int jj = occList[q];
                    if (jj > prevJ && jj < j) j = jj;
                }
                prevJ = j;
                float2 v = Vb2[j];
                u64 best = ~0ull;
                for (int e = bs; e < be; e++) {
                    int eIdx = e - bs;
                    if (eIdx < 64 && ((cons >> eIdx) & 1ull)) continue;
                    float2 u = bucketC[e];
                    float d = pdist(v.x, v.y, u.x, u.y);
                    u64 pk = ((u64)__float_as_uint(d) << 24)
                             | ((u64)(unsigned)ldsEnt[e] << 12) | (u64)(unsigned)eIdx;
                    if (pk < best) best = pk;
                }
                if (best != ~0ull) {
                    int eW = (int)(best & 0xFFFull);
                    matchU[j] = (short)((best >> 12) & 0xFFFull);
                    costPartial = __fadd_rn(costPartial,
                                            __uint_as_float((unsigned)(best >> 24)));
                    if (eW < 64) cons |= 1ull << eW;
                    if (o == 0) {
                        int base = evAx[j], w3 = 0;
                        for (int e = bs; e < be; e++) {
                            if (e - bs == eW) continue;
                            int idx = base + w3;
                            if (idx < EVcap) evPool[idx] = (unsigned short)e;
                            else if (idx - EVcap < spillCap)
                                evSpillB[idx - EVcap] = ldsEnt[e];
                            w3++;
                        }
                    }
                } else matchU[j] = -2;
            }
        }
    }
    __syncthreads();

    // ---- bg-step list compaction (ascending j) + vSteps from registers ----
    {
        bool need = (matchU[t] == (short)-2);
        u64 m = __ballot(need);
        if (lane == 0) wScrI[wv] = __popcll(m);
    }
    __syncthreads();
    if (t < 64) {
        int orig = (t < 16) ? wScrI[t] : 0;
        int v = orig;
        #pragma unroll
        for (int off = 1; off <= 8; off <<= 1) {
            int n = __shfl_up(v, off, 64);
            if (t >= off) v += n;
        }
        if (t < 16) wScrI[t] = v - orig;
        if (t == 15) scal[0] = v;
    }
    __syncthreads();
    {
        bool need = (matchU[t] == (short)-2);
        u64 m = __ballot(need);
        if (need) {
            int rank = __popcll(m & ((1ull << lane) - 1ull));
            int idx = wScrI[wv] + rank;
            if (idx < BGCAP) { bgListSh[idx] = (unsigned short)t; vSteps[idx] = vMe; }
        }
    }
    __syncthreads();

    // ---- staging: event slots -> contiguous pool right after bg0 ----
    const int bgCnt = min(scal[0], BGCAP);
    {
        const int nStage = min(totEv, EVcap);
        float2 sc[2]; unsigned short sp[2];
        #pragma unroll
        for (int k = 0; k < 2; k++) {             // constant-index regs (no scratch)
            int i = t + (k << 10);
            if (i < nStage) { int slot = evPool[i]; sp[k] = ldsEnt[slot]; sc[k] = bucketC[slot]; }
        }
        __syncthreads();
        #pragma unroll
        for (int k = 0; k < 2; k++) {
            int i = t + (k << 10);
            if (i < nStage) { ldsEnt[nBg0 + i] = sp[k]; bucketC[nBg0 + i] = sc[k]; }
        }
    }
    __syncthreads();

    // ---- beta: speculative argmins — 5 steps per wave share one LDS stream ----
    for (int s0 = wv; s0 < bgCnt; s0 += 80) {
        u64 best[5]; float vxq[5], vyq[5]; int limq[5];
        int maxLim = 0;
        #pragma unroll
        for (int q = 0; q < 5; q++) {
            int s = s0 + 16 * q;
            best[q] = ~0ull; limq[q] = 0; vxq[q] = 0.0f; vyq[q] = 0.0f;
            if (s < bgCnt) {
                int js = bgListSh[s];
                float2 v = vSteps[s];
                vxq[q] = v.x; vyq[q] = v.y;
                limq[q] = nBg0 + min((int)evAx[js], EVcap);
                maxLim = max(maxLim, limq[q]);
            }
        }
        for (int i = lane; i < maxLim; i += 64) {
            float2 c = bucketC[i];
            unsigned p = ldsEnt[i];
            #pragma unroll
            for (int q = 0; q < 5; q++) {
                if (i < limq[q]) {
                    float d = pdist(vxq[q], vyq[q], c.x, c.y);
                    u64 pk = ((u64)__float_as_uint(d) << 32) | p;
                    if (pk < best[q]) best[q] = pk;
                }
            }
        }
        #pragma unroll
        for (int q = 0; q < 5; q++) {
            int s = s0 + 16 * q;
            if (s < bgCnt) {
                int js = bgListSh[s];
                int ne = evAx[js];
                u64 bq = best[q];
                for (int ei = EVcap + lane; ei < ne; ei += 64) {  // spill tail
                    if (ei - EVcap >= spillCap) break;
                    unsigned p = evSpillB[ei - EVcap];
                    float2 c = Ub2[p];
                    float d = pdist(vxq[q], vyq[q], c.x, c.y);
                    u64 pk = ((u64)__float_as_uint(d) << 32) | p;
                    if (pk < bq) bq = pk;
                }
                #pragma unroll
                for (int off = 32; off >= 1; off >>= 1) {
                    u64 o = __shfl_xor(bq, off, 64);
                    if (o < bq) bq = o;
                }
                if (lane == 0) specWin[s] = bq;   // bEnd/occA dead -> alias
            }
        }
    }
    __syncthreads();

    // ---- 2c: O(1) duplicate-winner check via presence bitmap ----
    if (t < 128) dupBits[t] = 0;                  // bSt dead -> dupBits alias
    __syncthreads();
    if (t < bgCnt) {
        u64 w0 = specWin[t];
        if (w0 != ~0ull) {
            unsigned p = (unsigned)(w0 & 0xFFFFFFFFull);
            unsigned old = atomicOr(&dupBits[p >> 5], 1u << (p & 31));
            if (old & (1u << (p & 31))) scal[2] = 1;
        }
    }
    __syncthreads();

    float bgCost = 0.0f;
    if (scal[2] == 0) {
        // all winners distinct -> every speculative winner exact
        if (t < bgCnt) {
            int js = bgListSh[t];
            u64 w0 = specWin[t];
            if (w0 == ~0ull) matchU[js] = -1;
            else {
                matchU[js] = (short)(w0 & 0xFFFFFFFFull);
                costPartial = __fadd_rn(costPartial, __uint_as_float((unsigned)(w0 >> 32)));
            }
        }
    } else if (t < 64) {
        // sequential walk (rare): global bitmap, apply events, O(1) check
        for (int i = t; i < nBg0; i += 64) {      // bg0 bits from bg0 list
            int p = ldsEnt[i];
            atomicOr(&gbm[p >> 5], 1u << (p & 31));
        }
        __threadfence();
        int applied = 0;
        for (int s = 0; s < bgCnt; s++) {
            int js = bgListSh[s];
            int target = evAx[js];
            for (int base = applied; base < target; base += 64) {
                int idx = base + t;
                if (idx < target) {
                    int p = (idx < EVcap) ? (int)ldsEnt[nBg0 + idx]
                                          : (int)evSpillB[idx - EVcap];
                    atomicOr(&gbm[p >> 5], 1u << (p & 31));
                }
            }
            applied = target;
            __threadfence();
            u64 w0 = specWin[s];
            if (w0 == ~0ull) {
                if (t == 0) matchU[js] = -1;
            } else {
                int u = (int)(w0 & 0xFFFFFFFFull);
                bool setb = (gbm[u >> 5] >> (u & 31)) & 1u;
                if (setb) {
                    if (t == 0) {
                        matchU[js] = (short)u;
                        atomicAnd(&gbm[u >> 5], ~(1u << (u & 31)));
                        bgCost = __fadd_rn(bgCost, __uint_as_float((unsigned)(w0 >> 32)));
                    }
                } else {
                    float2 v = vSteps[s];
                    u64 best = ~0ull;
                    #pragma unroll
                    for (int i = 0; i < 2; i++) {
                        int wi = t * 2 + i;
                        unsigned bits = gbm[wi];
                        int pb = wi << 5;
                        while (bits) {
                            int bpos = __builtin_ctz(bits);
                            bits &= bits - 1;
                            int p = pb + bpos;
                            float2 uu = Ub2[p];
                            float d = pdist(v.x, v.y, uu.x, uu.y);
                            u64 pk = ((u64)__float_as_uint(d) << 32) | (unsigned)p;
                            if (pk < best) best = pk;
                        }
                    }
                    #pragma unroll
                    for (int off = 32; off >= 1; off >>= 1) {
                        u64 o = __shfl_xor(best, off, 64);
                        if (o < best) best = o;
                    }
                    if (t == 0) {
                        if (best != ~0ull) {
                            int u2 = (int)(best & 0xFFFFFFFFull);
                            matchU[js] = (short)u2;
                            atomicAnd(&gbm[u2 >> 5], ~(1u << (u2 & 31)));
                            bgCost = __fadd_rn(bgCost, __uint_as_float((unsigned)(best >> 32)));
                        } else matchU[js] = -1;
                    }
                }
                __threadfence();
            }
        }
    }
    __syncthreads();

    // ---- epilogue: cost reduction + outputs ----
    {
        float cp = costPartial;
        #pragma unroll
        for (int off = 32; off >= 1; off >>= 1) cp += __shfl_xor(cp, off, 64);
        if (lane == 0) wScrF[wv] = cp;
    }
    __syncthreads();
    if (t == 0) {
        float tot = bgCost;
        for (int i = 0; i < 16; ++i) tot = __fadd_rn(tot, wScrF[i]);
        out[(size_t)2 * B * NGT + b] = tot;
    }
    {
        int u = matchU[t];
        out[(size_t)b * NGT + t] = (float)u;
        out[(size_t)B * NGT + (size_t)b * NGT + t] = (u >= 0) ? (float)t : -1.0f;
    }
}

extern "C" void kernel_launch(void* const* d_in, const int* in_sizes, int n_in,
                              void* d_out, int out_size, void* d_ws, size_t ws_size,
                              hipStream_t stream) {
    const float* pred   = (const float*)d_in[0];
    const float* coords = (const float*)d_in[1];
    const int*   keys   = (const int*)d_in[2];
    const int*   masks  = (const int*)d_in[3];
    float* out = (float*)d_out;
    int B = in_sizes[2] / NGT;   // 8
    int useWs = (B == 8 && ws_size >= (size_t)WS_NEED) ? 1 : 0;
    int* hist = (int*)d_ws;
    unsigned short* labsP  = (unsigned short*)((char*)d_ws + LAB_OFF);
    unsigned short* spillP = (unsigned short*)((char*)d_ws + SPILL_OFF);
    unsigned*       gbmP   = (unsigned*)((char*)d_ws + GBM_OFF);
    if (useWs) {
        hipMemsetAsync(d_ws, 0, HIST_BYTES, stream);
        label_kernel<<<B * 8, 512, 0, stream>>>(pred, keys, masks, hist, labsP, gbmP);
    }
    matcher_kernel<<<B, 1024, 0, stream>>>(pred, coords, keys, masks, out,
                                           hist, labsP, spillP, gbmP, useWs, B);
}

// Round 11
// 196.186 us; speedup vs baseline: 1.1553x; 1.1553x over previous
//
#include <hip/hip_runtime.h>
#include <stdint.h>

// Problem constants: B=8, P=4096, N=1024, H=W=1024, labels 0..1024
#define PPTS 4096
#define NGT  1024
#define HH   1024
#define WW   1024
#define EVPOOL_CAP 2047   // LDS event-slot pool; totEv ~1950 (spill -> global ws)
#define BGCAP 160         // max bg steps (E[m] ~65)

// workspace layout: part u16[8][8][1025] (non-atomic partial hists);
// labels u16[8][4096]; spill u16[8][2048]; gbm u32[8][128]
#define PART_BYTES (8 * 8 * 1025 * 2)            // 131200
#define LAB_OFF    PART_BYTES
#define SPILL_OFF  (LAB_OFF + 8 * PPTS * 2)      // 196736
#define SPILL_CAP  2048
#define GBM_OFF    (SPILL_OFF + 8 * SPILL_CAP * 2)  // 229504
#define WS_NEED    (GBM_OFF + 8 * 128 * 4)

typedef unsigned long long u64;

__device__ __forceinline__ float pdist(float vx, float vy, float ux, float uy) {
    float dx = __fsub_rn(vx, ux);
    float dy = __fsub_rn(vy, uy);
    return __fsqrt_rn(__fadd_rn(__fmul_rn(dx, dx), __fmul_rn(dy, dy)));
}

// K1: 8 blocks per batch, 512 threads — labels (random mask gather) + LDS
// partial histogram written non-atomically to ws (no memset needed) + gbm zero.
__global__ __launch_bounds__(512) void label_kernel(
    const float* __restrict__ pred, const int* __restrict__ masks,
    unsigned short* __restrict__ part, unsigned short* __restrict__ labs,
    unsigned* __restrict__ gbm)
{
    __shared__ int lh[1025];
    const int blk = blockIdx.x, b = blk >> 3, sb = blk & 7;
    const int t = threadIdx.x;
    lh[t] = 0; lh[t + 512] = 0;
    if (t == 0) lh[1024] = 0;
    __syncthreads();
    const int p = (sb << 9) + t;
    float2 u = ((const float2*)(pred + (size_t)b * PPTS * 2))[p];
    int xi = (int)rintf(__fmul_rn(u.x, 1024.0f));   // rintf == jnp.round (half-even)
    int yi = (int)rintf(__fmul_rn(u.y, 1024.0f));
    xi = min(max(xi, 0), HH - 1);
    yi = min(max(yi, 0), WW - 1);
    int lab = (masks + (size_t)b * HH * WW)[xi * WW + yi];
    labs[(size_t)b * PPTS + p] = (unsigned short)lab;
    atomicAdd(&lh[lab], 1);
    if (sb == 7 && t < 128) gbm[b * 128 + t] = 0;   // fallback bitmap zero
    __syncthreads();
    unsigned short* Pp = part + (size_t)b * 8200 + sb * 1025;
    Pp[t] = (unsigned short)lh[t];
    Pp[t + 512] = (unsigned short)lh[t + 512];
    if (t == 0) Pp[1024] = (unsigned short)lh[1024];
}

// K2: one block per batch.
//  A/B : init; bucket counts = sum of 8 partials (useWs) or built from masks
//        (mono); keys-side occ/firstOcc/present via LDS atomics.
//  C   : quad-packed u64 exclusive scan (bg<<48|pr<<32|ev<<16|occ) -> bg-first
//        bucket starts, occ starts, per-step event offsets evAx.
//  D   : scatter coords+ids (bg0 list = [0,nBg0) for free), occ lists.
//  R   : thread j computes its RANK within its label by counting (no sort,
//        no local arrays -> no scratch); slow labels flagged.
//  BB  : flag-gated owner-sequential phase for slow labels (bucket>16/occ>250).
//  S2  : ROUNDS — round r: thread j (V[j] in register) does its label's r-th
//        occurrence argmin via consMask[l] (u16, unique writer per round);
//        round-0 winners emit dump events at evAx[j].
//  stg : event slots -> contiguous staged pool at [nBg0, nBg0+totEv).
//  beta: speculative per-step argmins, 5 steps per wave share one LDS stream.
//  2c  : O(1) dup-check (atomicOr presence) -> parallel commit (exact) or
//        sequential fallback walk (global bitmap, rare).
__global__ __launch_bounds__(1024) void matcher_kernel(
    const float* __restrict__ pred,    // [B,P,2]
    const float* __restrict__ coords,  // [B,N,2]
    const int*   __restrict__ keys,    // [B,N]
    const int*   __restrict__ masks,   // [B,H,W] (mono path only)
    float* __restrict__ out,           // [B*N src][B*N tgt][B total]
    const unsigned short* __restrict__ part, const unsigned short* __restrict__ labs,
    unsigned short* __restrict__ spill, unsigned* __restrict__ gbmAll,
    int useWs, int B)
{
    __shared__ __align__(16) char regU[32768];   // bucketC f2[4096] (bg0 + staged ev)
    __shared__ __align__(8)  char regE[8192];    // ldsEnt u16[4096]
    __shared__ __align__(8)  char regB[8200];    // bEnd[1025]+occA[1025] -> specWin u64[BGCAP]
    __shared__ __align__(8)  char regP[6144];    // firstOcc -> consMask u16[1025]+evPool u16[2047]; vSteps
    __shared__ __align__(4)  char regS[336];     // present u32[33] -> bgListSh u16[BGCAP]
    __shared__ __align__(8)  char regT[2048];    // bSt u16[1024] -> dupBits u32[128]
    __shared__ u64            wScr64[16];
    __shared__ u64            sTot;
    __shared__ unsigned short evAx[1024];        // per-step exclusive event offsets
    __shared__ unsigned short occList[NGT];
    __shared__ short          matchU[NGT];
    __shared__ int            scal[4];           // 0:bgCnt 1:maxR 2:dupFlag 3:slowFlag

    float2*         bucketC  = (float2*)regU;
    unsigned short* ldsEnt   = (unsigned short*)regE;
    int*            bEnd     = (int*)regB;
    int*            occA     = ((int*)regB) + 1025;
    u64*            specWin  = (u64*)regB;            // alias (post-rounds)
    int*            firstOcc = (int*)regP;            // dead after C
    unsigned short* consMask = (unsigned short*)regP; // [0,2050)
    unsigned short* evPool   = (unsigned short*)(regP + 2050); // [2050,6144)
    float2*         vSteps   = (float2*)regP;         // [0,1280) post-rounds
    unsigned*       present  = (unsigned*)regS;
    unsigned short* bgListSh = (unsigned short*)regS;
    unsigned short* bSt      = (unsigned short*)regT;
    unsigned*       dupBits  = (unsigned*)regT;       // alias (post-beta)
    int*   wScrI = (int*)wScr64;
    float* wScrF = (float*)wScr64;

    const int b = blockIdx.x;
    const int t = threadIdx.x;
    const int lane = t & 63, wv = t >> 6;
    const float2* Ub2 = (const float2*)(pred + (size_t)b * PPTS * 2);
    const float2* Vb2 = (const float2*)(coords + (size_t)b * NGT * 2);
    const int*   Kb = keys   + (size_t)b * NGT;
    unsigned short* evSpillB = spill + (size_t)b * SPILL_CAP;
    unsigned* gbm = gbmAll + (size_t)b * 128;
    const int spillCap = useWs ? SPILL_CAP : 0;

    // ---- A/B: init + bucket counts + key-side stats ----
    if (t == 0) { scal[0] = 0; scal[1] = 0; scal[2] = 0; scal[3] = 0; }
    const int k1 = Kb[t] + 1;                    // label of step j=t, in [1,1024]
    const float2 vMe = Vb2[t];                   // V of my own step — register!
    int lab[4]; float2 up[4];
    #pragma unroll
    for (int i = 0; i < 4; i++) up[i] = Ub2[t + (i << 10)];
    occA[t] = 0; firstOcc[t] = 0x7FFFFFFF;
    if (t == 0) { occA[1024] = 0; firstOcc[1024] = 0x7FFFFFFF; }
    if (t < 33) present[t] = 0;
    if (useWs) {
        const unsigned short* Pb = part + (size_t)b * 8200;
        int s = 0;
        #pragma unroll
        for (int sb = 0; sb < 8; sb++) s += Pb[sb * 1025 + t];
        bEnd[t] = s;
        if (t == 0) {
            int s2 = 0;
            #pragma unroll
            for (int sb = 0; sb < 8; sb++) s2 += Pb[sb * 1025 + 1024];
            bEnd[1024] = s2;
        }
        const unsigned short* Lb = labs + (size_t)b * PPTS;
        #pragma unroll
        for (int i = 0; i < 4; i++) lab[i] = Lb[t + (i << 10)];
    } else {
        bEnd[t] = 0;
        if (t == 0) bEnd[1024] = 0;
        if (t < 128) gbm[t] = 0;                 // mono: zero fallback bitmap
    }
    __syncthreads();
    atomicOr(&present[k1 >> 5], 1u << (k1 & 31));
    atomicAdd(&occA[k1], 1);
    atomicMin(&firstOcc[k1], t);
    if (!useWs) {
        const int* Mb = masks + (size_t)b * HH * WW;
        #pragma unroll
        for (int i = 0; i < 4; i++) {
            float2 u = up[i];
            int xi = (int)rintf(__fmul_rn(u.x, 1024.0f));
            int yi = (int)rintf(__fmul_rn(u.y, 1024.0f));
            xi = min(max(xi, 0), HH - 1);
            yi = min(max(yi, 0), WW - 1);
            lab[i] = Mb[xi * WW + yi];
            atomicAdd(&bEnd[lab[i]], 1);
        }
    }
    __syncthreads();

    // ---- C: quad-packed exclusive scan (bg<<48 | pr<<32 | ev<<16 | occ) ----
    {
        int c0 = bEnd[t], o0 = occA[t];
        bool pr0 = (present[t >> 5] >> (t & 31)) & 1u;
        int bCnt = bEnd[k1];
        int fo   = firstOcc[k1];
        int evc  = (fo == t && bCnt > 0) ? (bCnt - 1) : 0;
        u64 myv = (pr0 ? ((u64)(unsigned)c0 << 32) : ((u64)(unsigned)c0 << 48))
                  | ((u64)(unsigned)evc << 16) | (u64)(unsigned)o0;
        u64 add1 = 0; bool pr1 = false;
        if (t == 1023) {                          // fold label 1024 (no step 1024)
            int c1 = bEnd[1024], o1 = occA[1024];
            pr1 = present[32] & 1u;
            add1 = (pr1 ? ((u64)(unsigned)c1 << 32) : ((u64)(unsigned)c1 << 48))
                   | (u64)(unsigned)o1;
        }
        u64 tot = myv + add1;
        u64 inc = tot;
        #pragma unroll
        for (int off = 1; off < 64; off <<= 1) {
            u64 n = __shfl_up(inc, off, 64);
            if (lane >= off) inc += n;
        }
        if (lane == 63) wScr64[wv] = inc;
        __syncthreads();
        if (t < 16) {
            u64 v = wScr64[t], inc2 = v;
            #pragma unroll
            for (int off = 1; off < 16; off <<= 1) {
                u64 n = __shfl_up(inc2, off, 64);
                if (t >= off) inc2 += n;
            }
            wScr64[t] = inc2 - v;
            if (t == 15) sTot = inc2;
        }
        __syncthreads();
        u64 excl = wScr64[wv] + inc - tot;
        int nBg0v = (int)(sTot >> 48);
        int bgS = (int)(excl >> 48);
        int prS = (int)((excl >> 32) & 0xFFFF);
        int evS = (int)((excl >> 16) & 0xFFFF);
        int ocS = (int)(excl & 0xFFFF);
        int start0 = pr0 ? (nBg0v + prS) : bgS;
        bEnd[t] = start0;                         // scatter cursor (start)
        occA[t] = ocS;
        evAx[t] = (unsigned short)evS;
        if (t >= 1) bSt[t - 1] = (unsigned short)start0;  // start of label t
        if (t == 1023) {
            u64 ex1 = excl + myv;
            int bgS1 = (int)(ex1 >> 48);
            int prS1 = (int)((ex1 >> 32) & 0xFFFF);
            int start1 = pr1 ? (nBg0v + prS1) : bgS1;
            bEnd[1024] = start1; occA[1024] = (int)(ex1 & 0xFFFF);
            bSt[1023] = (unsigned short)start1;
        }
    }
    __syncthreads();
    const int nBg0  = (int)(sTot >> 48);
    const int totEv = (int)((sTot >> 16) & 0xFFFF);
    const int EVcap = min(EVPOOL_CAP, PPTS - nBg0);

    // ---- D: scatter coords+ids (bg labels land in [0,nBg0)), occ lists ----
    consMask[t] = 0;
    if (t == 0) consMask[1024] = 0;   // incl. label 1024
    #pragma unroll
    for (int i = 0; i < 4; i++) {
        int p = t + (i << 10);
        int slot = atomicAdd(&bEnd[lab[i]], 1);
        ldsEnt[slot] = (unsigned short)p;
        bucketC[slot] = up[i];
    }
    {
        int slot = atomicAdd(&occA[k1], 1);
        occList[slot] = (unsigned short)t;
    }
    __syncthreads();

    // ---- R: rank by counting (no sort, no local arrays) ----
    float costPartial = 0.0f;
    unsigned char myRank = 0xFE;
    {
        const int os = occA[k1 - 1], oe = occA[k1];   // post-scatter: label k1's list
        const int bn = (int)bEnd[k1] - (int)bSt[k1 - 1];
        const int occCnt = oe - os;
        bool slowLab = (bn > 16) || (occCnt > 250);
        int vmax = 0;
        if (slowLab) scal[3] = 1;
        else {
            int rank = 0;
            for (int q = os; q < oe; q++)
                if ((int)occList[q] < t) rank++;
            myRank = (unsigned char)rank;
            vmax = rank + 1;
        }
        #pragma unroll
        for (int off = 32; off >= 1; off >>= 1)
            vmax = max(vmax, __shfl_xor(vmax, off, 64));
        if (lane == 0) wScrI[wv] = vmax;
    }
    __syncthreads();
    if (t < 16) {
        int v = wScrI[t];
        #pragma unroll
        for (int off = 8; off >= 1; off >>= 1) v = max(v, __shfl_xor(v, off, 64));
        if (t == 0) scal[1] = v;
    }
    __syncthreads();

    // ---- BB: slow labels (bucket>16 or occ>250), owner-sequential (rare) ----
    if (scal[3]) {
        const int os = occA[t], oe = occA[t + 1];     // owner of label t+1
        const int occCnt = oe - os;
        const int bs = bSt[t], be = bEnd[t + 1];
        if (occCnt > 0 && ((be - bs) > 16 || occCnt > 250)) {
            u64 cons = 0;
            int prevJ = -1;
            for (int o = 0; o < occCnt; o++) {
                int j = 0x7FFFFFFF;                   // next smallest j
                for (int q = os; q < oe; q++) {
                    int jj = occList[q];
                    if (jj > prevJ && jj < j) j = jj;
                }
                prevJ = j;
                float2 v = Vb2[j];
                u64 best = ~0ull;
                for (int e = bs; e < be; e++) {
                    int eIdx = e - bs;
                    int p = ldsEnt[e];
                    bool consd;
                    if (eIdx < 64) consd = (cons >> eIdx) & 1ull;
                    else {                            // exact fallback (bucket>64)
                        consd = false;
                        for (int q2 = os; q2 < oe; q2++) {
                            int jj2 = occList[q2];
                            if (jj2 < j && (int)matchU[jj2] == p) { consd = true; break; }
                        }
                    }
                    if (consd) continue;
                    float2 u = bucketC[e];
                    float d = pdist(v.x, v.y, u.x, u.y);
                    u64 pk = ((u64)__float_as_uint(d) << 24)
                             | ((u64)(unsigned)p << 12) | (u64)(unsigned)eIdx;
                    if (pk < best) best = pk;
                }
                if (best != ~0ull) {
                    int eW = (int)(best & 0xFFFull);
                    matchU[j] = (short)((best >> 12) & 0xFFFull);
                    costPartial = __fadd_rn(costPartial,
                                            __uint_as_float((unsigned)(best >> 24)));
                    if (eW < 64) cons |= 1ull << eW;
                    if (o == 0) {
                        int base = evAx[j], w3 = 0;
                        for (int e = bs; e < be; e++) {
                            if (e - bs == eW) continue;
                            int idx = base + w3;
                            if (idx < EVcap) evPool[idx] = (unsigned short)e;
                            else if (idx - EVcap < spillCap)
                                evSpillB[idx - EVcap] = ldsEnt[e];
                            w3++;
                        }
                    }
                } else matchU[j] = -2;
            }
        }
        __syncthreads();
    }

    // ---- S2: rounds — thread j handles its label's r-th occurrence ----
    {
        const int maxR = scal[1];
        const int bs = bSt[k1 - 1], be = bEnd[k1];
        for (int r = 0; r < maxR; r++) {
            if (myRank == (unsigned char)r) {
                unsigned cm = consMask[k1];
                u64 best = ~0ull;
                for (int e = bs; e < be; e++) {
                    int eIdx = e - bs;
                    if ((cm >> eIdx) & 1u) continue;
                    float2 u = bucketC[e];
                    float d = pdist(vMe.x, vMe.y, u.x, u.y);
                    u64 pk = ((u64)__float_as_uint(d) << 24)
                             | ((u64)(unsigned)ldsEnt[e] << 12) | (u64)(unsigned)eIdx;
                    if (pk < best) best = pk;
                }
                if (best != ~0ull) {
                    int eW = (int)(best & 0xFFFull);
                    matchU[t] = (short)((best >> 12) & 0xFFFull);
                    costPartial = __fadd_rn(costPartial,
                                            __uint_as_float((unsigned)(best >> 24)));
                    consMask[k1] = (unsigned short)(cm | (1u << eW)); // unique writer
                    if (r == 0) {                 // first occurrence: emit dumps
                        int base = evAx[t], w3 = 0;
                        for (int e = bs; e < be; e++) {
                            if (e - bs == eW) continue;
                            int idx = base + w3;
                            if (idx < EVcap) evPool[idx] = (unsigned short)e;
                            else if (idx - EVcap < spillCap)
                                evSpillB[idx - EVcap] = ldsEnt[e];
                            w3++;
                        }
                    }
                } else matchU[t] = -2;
            }
            __syncthreads();
        }
    }

    // ---- bg-step list compaction (ascending j) + vSteps from registers ----
    {
        bool need = (matchU[t] == (short)-2);
        u64 m = __ballot(need);
        if (lane == 0) wScrI[wv] = __popcll(m);
    }
    __syncthreads();
    if (t < 64) {
        int orig = (t < 16) ? wScrI[t] : 0;
        int v = orig;
        #pragma unroll
        for (int off = 1; off <= 8; off <<= 1) {
            int n = __shfl_up(v, off, 64);
            if (t >= off) v += n;
        }
        if (t < 16) wScrI[t] = v - orig;
        if (t == 15) scal[0] = v;
    }
    __syncthreads();
    {
        bool need = (matchU[t] == (short)-2);
        u64 m = __ballot(need);
        if (need) {
            int rank = __popcll(m & ((1ull << lane) - 1ull));
            int idx = wScrI[wv] + rank;
            if (idx < BGCAP) { bgListSh[idx] = (unsigned short)t; vSteps[idx] = vMe; }
        }
    }
    __syncthreads();

    // ---- staging: event slots -> contiguous pool right after bg0 ----
    const int bgCnt = min(scal[0], BGCAP);
    {
        const int nStage = min(totEv, EVcap);
        float2 sc[2]; unsigned short sp[2];
        #pragma unroll
        for (int k = 0; k < 2; k++) {             // constant-index regs (no scratch)
            int i = t + (k << 10);
            if (i < nStage) { int slot = evPool[i]; sp[k] = ldsEnt[slot]; sc[k] = bucketC[slot]; }
        }
        __syncthreads();
        #pragma unroll
        for (int k = 0; k < 2; k++) {
            int i = t + (k << 10);
            if (i < nStage) { ldsEnt[nBg0 + i] = sp[k]; bucketC[nBg0 + i] = sc[k]; }
        }
    }
    __syncthreads();

    // ---- beta: speculative argmins — 5 steps per wave share one LDS stream ----
    for (int s0 = wv; s0 < bgCnt; s0 += 80) {
        u64 best[5]; float vxq[5], vyq[5]; int limq[5];
        int maxLim = 0;
        #pragma unroll
        for (int q = 0; q < 5; q++) {
            int s = s0 + 16 * q;
            best[q] = ~0ull; limq[q] = 0; vxq[q] = 0.0f; vyq[q] = 0.0f;
            if (s < bgCnt) {
                int js = bgListSh[s];
                float2 v = vSteps[s];
                vxq[q] = v.x; vyq[q] = v.y;
                limq[q] = nBg0 + min((int)evAx[js], EVcap);
                maxLim = max(maxLim, limq[q]);
            }
        }
        for (int i = lane; i < maxLim; i += 64) {
            float2 c = bucketC[i];
            unsigned p = ldsEnt[i];
            #pragma unroll
            for (int q = 0; q < 5; q++) {
                if (i < limq[q]) {
                    float d = pdist(vxq[q], vyq[q], c.x, c.y);
                    u64 pk = ((u64)__float_as_uint(d) << 32) | p;
                    if (pk < best[q]) best[q] = pk;
                }
            }
        }
        #pragma unroll
        for (int q = 0; q < 5; q++) {
            int s = s0 + 16 * q;
            if (s < bgCnt) {
                int js = bgListSh[s];
                int ne = evAx[js];
                u64 bq = best[q];
                for (int ei = EVcap + lane; ei < ne; ei += 64) {  // spill tail
                    if (ei - EVcap >= spillCap) break;
                    unsigned p = evSpillB[ei - EVcap];
                    float2 c = Ub2[p];
                    float d = pdist(vxq[q], vyq[q], c.x, c.y);
                    u64 pk = ((u64)__float_as_uint(d) << 32) | p;
                    if (pk < bq) bq = pk;
                }
                #pragma unroll
                for (int off = 32; off >= 1; off >>= 1) {
                    u64 o = __shfl_xor(bq, off, 64);
                    if (o < bq) bq = o;
                }
                if (lane == 0) specWin[s] = bq;   // bEnd/occA dead -> alias
            }
        }
    }
    __syncthreads();

    // ---- 2c: O(1) duplicate-winner check via presence bitmap ----
    if (t < 128) dupBits[t] = 0;                  // bSt dead -> dupBits alias
    __syncthreads();
    if (t < bgCnt) {
        u64 w0 = specWin[t];
        if (w0 != ~0ull) {
            unsigned p = (unsigned)(w0 & 0xFFFFFFFFull);
            unsigned old = atomicOr(&dupBits[p >> 5], 1u << (p & 31));
            if (old & (1u << (p & 31))) scal[2] = 1;
        }
    }
    __syncthreads();

    float bgCost = 0.0f;
    if (scal[2] == 0) {
        // all winners distinct -> every speculative winner exact
        if (t < bgCnt) {
            int js = bgListSh[t];
            u64 w0 = specWin[t];
            if (w0 == ~0ull) matchU[js] = -1;
            else {
                matchU[js] = (short)(w0 & 0xFFFFFFFFull);
                costPartial = __fadd_rn(costPartial, __uint_as_float((unsigned)(w0 >> 32)));
            }
        }
    } else if (t < 64) {
        // sequential walk (rare): global bitmap, apply events, O(1) check
        for (int i = t; i < nBg0; i += 64) {      // bg0 bits from bg0 list
            int p = ldsEnt[i];
            atomicOr(&gbm[p >> 5], 1u << (p & 31));
        }
        __threadfence();
        int applied = 0;
        for (int s = 0; s < bgCnt; s++) {
            int js = bgListSh[s];
            int target = evAx[js];
            for (int base = applied; base < target; base += 64) {
                int idx = base + t;
                if (idx < target) {
                    int p = (idx < EVcap) ? (int)ldsEnt[nBg0 + idx]
                                          : (int)evSpillB[idx - EVcap];
                    atomicOr(&gbm[p >> 5], 1u << (p & 31));
                }
            }
            applied = target;
            __threadfence();
            u64 w0 = specWin[s];
            if (w0 == ~0ull) {
                if (t == 0) matchU[js] = -1;
            } else {
                int u = (int)(w0 & 0xFFFFFFFFull);
                bool setb = (gbm[u >> 5] >> (u & 31)) & 1u;
                if (setb) {
                    if (t == 0) {
                        matchU[js] = (short)u;
                        atomicAnd(&gbm[u >> 5], ~(1u << (u & 31)));
                        bgCost = __fadd_rn(bgCost, __uint_as_float((unsigned)(w0 >> 32)));
                    }
                } else {
                    float2 v = vSteps[s];
                    u64 best = ~0ull;
                    #pragma unroll
                    for (int i = 0; i < 2; i++) {
                        int wi = t * 2 + i;
                        unsigned bits = gbm[wi];
                        int pb = wi << 5;
                        while (bits) {
                            int bpos = __builtin_ctz(bits);
                            bits &= bits - 1;
                            int p = pb + bpos;
                            float2 uu = Ub2[p];
                            float d = pdist(v.x, v.y, uu.x, uu.y);
                            u64 pk = ((u64)__float_as_uint(d) << 32) | (unsigned)p;
                            if (pk < best) best = pk;
                        }
                    }
                    #pragma unroll
                    for (int off = 32; off >= 1; off >>= 1) {
                        u64 o = __shfl_xor(best, off, 64);
                        if (o < best) best = o;
                    }
                    if (t == 0) {
                        if (best != ~0ull) {
                            int u2 = (int)(best & 0xFFFFFFFFull);
                            matchU[js] = (short)u2;
                            atomicAnd(&gbm[u2 >> 5], ~(1u << (u2 & 31)));
                            bgCost = __fadd_rn(bgCost, __uint_as_float((unsigned)(best >> 32)));
                        } else matchU[js] = -1;
                    }
                }
                __threadfence();
            }
        }
    }
    __syncthreads();

    // ---- epilogue: cost reduction + outputs ----
    {
        float cp = costPartial;
        #pragma unroll
        for (int off = 32; off >= 1; off >>= 1) cp += __shfl_xor(cp, off, 64);
        if (lane == 0) wScrF[wv] = cp;
    }
    __syncthreads();
    if (t == 0) {
        float tot = bgCost;
        for (int i = 0; i < 16; ++i) tot = __fadd_rn(tot, wScrF[i]);
        out[(size_t)2 * B * NGT + b] = tot;
    }
    {
        int u = matchU[t];
        out[(size_t)b * NGT + t] = (float)u;
        out[(size_t)B * NGT + (size_t)b * NGT + t] = (u >= 0) ? (float)t : -1.0f;
    }
}

extern "C" void kernel_launch(void* const* d_in, const int* in_sizes, int n_in,
                              void* d_out, int out_size, void* d_ws, size_t ws_size,
                              hipStream_t stream) {
    const float* pred   = (const float*)d_in[0];
    const float* coords = (const float*)d_in[1];
    const int*   keys   = (const int*)d_in[2];
    const int*   masks  = (const int*)d_in[3];
    float* out = (float*)d_out;
    int B = in_sizes[2] / NGT;   // 8
    int useWs = (B == 8 && ws_size >= (size_t)WS_NEED) ? 1 : 0;
    unsigned short* partP  = (unsigned short*)d_ws;
    unsigned short* labsP  = (unsigned short*)((char*)d_ws + LAB_OFF);
    unsigned short* spillP = (unsigned short*)((char*)d_ws + SPILL_OFF);
    unsigned*       gbmP   = (unsigned*)((char*)d_ws + GBM_OFF);
    if (useWs) {
        label_kernel<<<B * 8, 512, 0, stream>>>(pred, masks, partP, labsP, gbmP);
    }
    matcher_kernel<<<B, 1024, 0, stream>>>(pred, coords, keys, masks, out,
                                           partP, labsP, spillP, gbmP, useWs, B);
}

// Round 12
// 159.816 us; speedup vs baseline: 1.4182x; 1.2276x over previous
//
#include <hip/hip_runtime.h>
#include <stdint.h>

// Problem constants: B=8, P=4096, N=1024, H=W=1024, labels 0..1024
#define PPTS 4096
#define NGT  1024
#define HH   1024
#define WW   1024
#define EVPOOL_CAP 3072   // LDS event-slot pool; first-dump events ~1900 < cap
#define BGCAP 160         // max bg steps (E[m] ~65)
#define RB 12             // register-bucket cap in 1a (P[bucket>12] ~ 4e-4)

// workspace layout: part u16[8][8][1025] (non-atomic partial hists);
// labels u16[8][4096]; spill u16[8][2048]
#define PART_BYTES (8 * 8 * 1025 * 2)            // 131200
#define LAB_OFF    PART_BYTES
#define SPILL_OFF  (LAB_OFF + 8 * PPTS * 2)      // 196736
#define SPILL_CAP  2048
#define WS_NEED    (SPILL_OFF + 8 * SPILL_CAP * 2)

typedef unsigned long long u64;

__device__ __forceinline__ float pdist(float vx, float vy, float ux, float uy) {
    float dx = __fsub_rn(vx, ux);
    float dy = __fsub_rn(vy, uy);
    return __fsqrt_rn(__fadd_rn(__fmul_rn(dx, dx), __fmul_rn(dy, dy)));
}

// K1: 8 blocks per batch, 512 threads — labels (random mask gather) + LDS
// histogram written non-atomically to ws as per-sub-block partials (no memset).
__global__ __launch_bounds__(512) void label_kernel(
    const float* __restrict__ pred, const int* __restrict__ masks,
    unsigned short* __restrict__ part, unsigned short* __restrict__ labs)
{
    __shared__ int lh[1025];
    const int blk = blockIdx.x, b = blk >> 3, sb = blk & 7;
    const int t = threadIdx.x;
    lh[t] = 0; lh[t + 512] = 0;
    if (t == 0) lh[1024] = 0;
    __syncthreads();
    const int p = (sb << 9) + t;
    float2 u = ((const float2*)(pred + (size_t)b * PPTS * 2))[p];
    int xi = (int)rintf(__fmul_rn(u.x, 1024.0f));   // rintf == jnp.round (half-even)
    int yi = (int)rintf(__fmul_rn(u.y, 1024.0f));
    xi = min(max(xi, 0), HH - 1);
    yi = min(max(yi, 0), WW - 1);
    int lab = (masks + (size_t)b * HH * WW)[xi * WW + yi];
    labs[(size_t)b * PPTS + p] = (unsigned short)lab;
    atomicAdd(&lh[lab], 1);
    __syncthreads();
    unsigned short* Pp = part + (size_t)b * 8200 + sb * 1025;
    Pp[t] = (unsigned short)lh[t];
    Pp[t + 512] = (unsigned short)lh[t + 512];
    if (t == 0) Pp[1024] = (unsigned short)lh[1024];
}

// K2: one block per batch — r8 structure (best measured, scratch-free).
//  A/B : bucket counts = sum of 8 partials (useWs) or mask gather (mono);
//        key-side occ/firstOcc/present via LDS atomics.
//  C   : quad-packed u64 exclusive scan (bg<<48|pr<<32|ev<<16|occ).
//  D   : scatter coords+ids (bg0 list = [0,nBg0) for free), occ lists.
//  1a  : owner-per-label inside-match chains (register-resident buckets),
//        first-occurrence dump-event emission at evAx[j].
//  stg : event slots -> contiguous staged pool at [nBg0, nBg0+totEv).
//  beta: speculative per-step argmins, 5 steps per wave share one LDS stream.
//  2c  : dup-check -> parallel commit (exact) or sequential fallback walk.
__global__ __launch_bounds__(1024) void matcher_kernel(
    const float* __restrict__ pred,    // [B,P,2]
    const float* __restrict__ coords,  // [B,N,2]
    const int*   __restrict__ keys,    // [B,N]
    const int*   __restrict__ masks,   // [B,H,W] (mono path only)
    float* __restrict__ out,           // [B*N src][B*N tgt][B total]
    const unsigned short* __restrict__ part, const unsigned short* __restrict__ labs,
    unsigned short* __restrict__ spill, int useWs, int B)
{
    __shared__ __align__(16) char regU[32768];          // bucketC f2[4096] (bg0 + staged ev)
    __shared__ __align__(8)  char regE[8192];           // ldsEnt u16[4096]
    __shared__ __align__(8)  char regB[8200];           // bEnd+occA -> specWin u64[BGCAP]
    __shared__ __align__(8)  char regP[2 * EVPOOL_CAP]; // firstOcc i32 -> evPool u16 -> vSteps
    __shared__ __align__(4)  char regS[384];            // present u32[33] -> bgListSh u16[BGCAP]
    __shared__ u64            wScr64[16];
    __shared__ u64            sTot;
    __shared__ unsigned short evAx[1024];
    __shared__ unsigned short occList[NGT];
    __shared__ short          matchU[NGT];
    __shared__ unsigned       bgbits[PPTS / 32];
    __shared__ unsigned short bSt[1024];
    __shared__ int            scal[4];                  // 0:bgCnt 2:dupFlag

    float2*         bucketC  = (float2*)regU;
    unsigned short* ldsEnt   = (unsigned short*)regE;
    int*            bEnd     = (int*)regB;
    int*            occA     = ((int*)regB) + 1025;
    u64*            specWin  = (u64*)regB;
    int*            firstOcc = (int*)regP;
    unsigned short* evPool   = (unsigned short*)regP;
    float2*         vSteps   = (float2*)regP;
    unsigned*       present  = (unsigned*)regS;
    unsigned short* bgListSh = (unsigned short*)regS;
    int*   wScrI = (int*)wScr64;
    float* wScrF = (float*)wScr64;

    const int b = blockIdx.x;
    const int t = threadIdx.x;
    const int lane = t & 63, wv = t >> 6;
    const float* Ub = pred   + (size_t)b * PPTS * 2;
    const float2* Ub2 = (const float2*)Ub;
    const float* Vb = coords + (size_t)b * NGT * 2;
    const int*   Kb = keys   + (size_t)b * NGT;
    unsigned short* evSpillB = spill + (size_t)b * SPILL_CAP;
    const int spillCap = useWs ? SPILL_CAP : 0;

    // ---- A/B: init + bucket counts + key-side stats (LDS atomics) ----
    if (t < PPTS / 32) bgbits[t] = 0;
    if (t == 0) { scal[0] = 0; scal[2] = 0; }
    const int k1 = Kb[t] + 1;                    // label of step j=t, in [1,1024]
    int lab[4]; float2 up[4];
    #pragma unroll
    for (int i = 0; i < 4; i++) up[i] = Ub2[t + (i << 10)];
    occA[t] = 0; firstOcc[t] = 0x7FFFFFFF;
    if (t == 0) { occA[1024] = 0; firstOcc[1024] = 0x7FFFFFFF; }
    if (t < 33) present[t] = 0;
    if (useWs) {
        const unsigned short* Pb = part + (size_t)b * 8200;
        int s = 0;
        #pragma unroll
        for (int sb = 0; sb < 8; sb++) s += Pb[sb * 1025 + t];
        bEnd[t] = s;
        if (t == 0) {
            int s2 = 0;
            #pragma unroll
            for (int sb = 0; sb < 8; sb++) s2 += Pb[sb * 1025 + 1024];
            bEnd[1024] = s2;
        }
        const unsigned short* Lb = labs + (size_t)b * PPTS;
        #pragma unroll
        for (int i = 0; i < 4; i++) lab[i] = Lb[t + (i << 10)];
    } else {
        bEnd[t] = 0;
        if (t == 0) bEnd[1024] = 0;
    }
    __syncthreads();
    atomicOr(&present[k1 >> 5], 1u << (k1 & 31));
    atomicAdd(&occA[k1], 1);
    atomicMin(&firstOcc[k1], t);
    if (!useWs) {
        const int* Mb = masks + (size_t)b * HH * WW;
        #pragma unroll
        for (int i = 0; i < 4; i++) {
            float2 u = up[i];
            int xi = (int)rintf(__fmul_rn(u.x, 1024.0f));
            int yi = (int)rintf(__fmul_rn(u.y, 1024.0f));
            xi = min(max(xi, 0), HH - 1);
            yi = min(max(yi, 0), WW - 1);
            lab[i] = Mb[xi * WW + yi];
            atomicAdd(&bEnd[lab[i]], 1);
        }
    }
    __syncthreads();

    // ---- C: quad-packed exclusive scan (bg<<48 | pr<<32 | ev<<16 | occ) ----
    {
        int c0 = bEnd[t], o0 = occA[t];
        bool pr0 = (present[t >> 5] >> (t & 31)) & 1u;
        int bCnt = bEnd[k1];
        int fo   = firstOcc[k1];
        int evc  = (fo == t && bCnt > 0) ? (bCnt - 1) : 0;
        u64 myv = (pr0 ? ((u64)(unsigned)c0 << 32) : ((u64)(unsigned)c0 << 48))
                  | ((u64)(unsigned)evc << 16) | (u64)(unsigned)o0;
        u64 add1 = 0; bool pr1 = false;
        if (t == 1023) {                          // fold label 1024 (no step 1024)
            int c1 = bEnd[1024], o1 = occA[1024];
            pr1 = present[32] & 1u;
            add1 = (pr1 ? ((u64)(unsigned)c1 << 32) : ((u64)(unsigned)c1 << 48))
                   | (u64)(unsigned)o1;
        }
        u64 tot = myv + add1;
        u64 inc = tot;
        #pragma unroll
        for (int off = 1; off < 64; off <<= 1) {
            u64 n = __shfl_up(inc, off, 64);
            if (lane >= off) inc += n;
        }
        if (lane == 63) wScr64[wv] = inc;
        __syncthreads();
        if (t < 16) {
            u64 v = wScr64[t], inc2 = v;
            #pragma unroll
            for (int off = 1; off < 16; off <<= 1) {
                u64 n = __shfl_up(inc2, off, 64);
                if (t >= off) inc2 += n;
            }
            wScr64[t] = inc2 - v;
            if (t == 15) sTot = inc2;
        }
        __syncthreads();
        u64 excl = wScr64[wv] + inc - tot;
        int nBg0v = (int)(sTot >> 48);
        int bgS = (int)(excl >> 48);
        int prS = (int)((excl >> 32) & 0xFFFF);
        int evS = (int)((excl >> 16) & 0xFFFF);
        int ocS = (int)(excl & 0xFFFF);
        int start0 = pr0 ? (nBg0v + prS) : bgS;
        bEnd[t] = start0;
        occA[t] = ocS;
        evAx[t] = (unsigned short)evS;
        if (t >= 1) bSt[t - 1] = (unsigned short)start0;
        if (t == 1023) {
            u64 ex1 = excl + myv;
            int bgS1 = (int)(ex1 >> 48);
            int prS1 = (int)((ex1 >> 32) & 0xFFFF);
            int start1 = pr1 ? (nBg0v + prS1) : bgS1;
            bEnd[1024] = start1; occA[1024] = (int)(ex1 & 0xFFFF);
            bSt[1023] = (unsigned short)start1;
        }
    }
    __syncthreads();
    const int nBg0  = (int)(sTot >> 48);
    const int totEv = (int)((sTot >> 16) & 0xFFFF);
    const int EVcap = min(EVPOOL_CAP, PPTS - nBg0);

    // ---- D: scatter coords+ids (bg labels land in [0,nBg0)), occ lists ----
    #pragma unroll
    for (int i = 0; i < 4; i++) {
        int p = t + (i << 10);
        int slot = atomicAdd(&bEnd[lab[i]], 1);
        ldsEnt[slot] = (unsigned short)p;
        bucketC[slot] = up[i];
        if (!((present[lab[i] >> 5] >> (lab[i] & 31)) & 1u))
            atomicOr(&bgbits[p >> 5], 1u << (p & 31));   // fallback path only
    }
    {
        int slot = atomicAdd(&occA[k1], 1);
        occList[slot] = (unsigned short)t;
    }
    __syncthreads();

    // ---- 1a: per-label inside-match chains (register-resident buckets) ----
    float costPartial = 0.0f;
    {
        const int l = t + 1;
        const int os = occA[t], oe = occA[l];
        for (int i = os + 1; i < oe; i++) {          // sort occurrences ascending
            unsigned short v = occList[i];
            int k = i - 1;
            while (k >= os && occList[k] > v) { occList[k + 1] = occList[k]; k--; }
            occList[k + 1] = v;
        }
        const int bs = bSt[t], be = bEnd[l];
        const int bn = be - bs;
        if (oe > os && bn > 0 && bn <= RB) {
            // fast path: bucket in registers, argmin is pure predicated VALU
            float rcx[RB], rcy[RB]; int rp[RB];
            #pragma unroll
            for (int k = 0; k < RB; k++)
                if (k < bn) { float2 c = bucketC[bs + k]; rcx[k] = c.x; rcy[k] = c.y;
                              rp[k] = ldsEnt[bs + k]; }
            unsigned cons = 0;
            for (int o = os; o < oe; o++) {
                int j = occList[o];
                float2 v = ((const float2*)Vb)[j];
                u64 best = ~0ull;
                #pragma unroll
                for (int k = 0; k < RB; k++) {
                    if (k < bn && !((cons >> k) & 1u)) {
                        float d = pdist(v.x, v.y, rcx[k], rcy[k]);
                        u64 pk = ((u64)__float_as_uint(d) << 24)
                                 | ((u64)(unsigned)rp[k] << 12) | (u64)(unsigned)k;
                        if (pk < best) best = pk;
                    }
                }
                if (best != ~0ull) {
                    int eW = (int)(best & 0xFFFull);
                    matchU[j] = (short)((best >> 12) & 0xFFFull);
                    costPartial = __fadd_rn(costPartial,
                                            __uint_as_float((unsigned)(best >> 24)));
                    cons |= 1u << eW;
                    if (o == os) {                    // first occurrence: emit dumps
                        int base = evAx[j];
                        #pragma unroll
                        for (int k = 0; k < RB; k++) {
                            if (k < bn && k != eW) {
                                int idx = base + k - (k > eW ? 1 : 0);
                                if (idx < EVcap) evPool[idx] = (unsigned short)(bs + k);
                                else if (idx - EVcap < spillCap)
                                    evSpillB[idx - EVcap] = (unsigned short)rp[k];
                            }
                        }
                    }
                } else matchU[j] = -2;
            }
        } else if (oe > os) {
            // generic path: big buckets (rare) or empty bucket
            u64 cons = 0;
            for (int o = os; o < oe; o++) {
                int j = occList[o];
                float2 v = ((const float2*)Vb)[j];
                u64 best = ~0ull;
                int avail = 0;
                for (int e = bs; e < be; e++) {
                    int eIdx = e - bs;
                    int p = ldsEnt[e];
                    bool consd;
                    if (eIdx < 64) consd = (cons >> eIdx) & 1ull;
                    else {
                        consd = false;
                        for (int o2 = os; o2 < o; o2++)
                            if ((int)matchU[occList[o2]] == p) { consd = true; break; }
                    }
                    if (consd) continue;
                    avail++;
                    float2 u = bucketC[e];
                    float d = pdist(v.x, v.y, u.x, u.y);
                    u64 pk = ((u64)__float_as_uint(d) << 24) | ((u64)(unsigned)p << 12)
                             | (u64)(unsigned)eIdx;
                    if (pk < best) best = pk;
                }
                if (avail > 0) {
                    int eW = (int)(best & 0xFFFull);
                    matchU[j] = (short)((best >> 12) & 0xFFFull);
                    costPartial = __fadd_rn(costPartial,
                                            __uint_as_float((unsigned)(best >> 24)));
                    if (eW < 64) cons |= 1ull << eW;
                    if (o == os) {
                        int base = evAx[j], w3 = 0;
                        for (int e = bs; e < be; e++) {
                            if (e - bs == eW) continue;
                            int idx = base + w3;
                            if (idx < EVcap) evPool[idx] = (unsigned short)e;
                            else if (idx - EVcap < spillCap)
                                evSpillB[idx - EVcap] = ldsEnt[e];
                            w3++;
                        }
                    }
                } else matchU[j] = -2;
            }
        }
    }
    __syncthreads();

    // ---- bg-step list compaction (ascending j) ----
    {
        bool need = (matchU[t] == (short)-2);
        u64 m = __ballot(need);
        if (lane == 0) wScrI[wv] = __popcll(m);
    }
    __syncthreads();
    if (t < 64) {
        int orig = (t < 16) ? wScrI[t] : 0;
        int v = orig;
        #pragma unroll
        for (int off = 1; off <= 8; off <<= 1) {
            int n = __shfl_up(v, off, 64);
            if (t >= off) v += n;
        }
        if (t < 16) wScrI[t] = v - orig;
        if (t == 15) scal[0] = v;
    }
    __syncthreads();
    {
        bool need = (matchU[t] == (short)-2);
        u64 m = __ballot(need);
        if (need) {
            int rank = __popcll(m & ((1ull << lane) - 1ull));
            int idx = wScrI[wv] + rank;
            if (idx < BGCAP) bgListSh[idx] = (unsigned short)t;
        }
    }
    __syncthreads();

    // ---- staging: event slots -> contiguous pool right after bg0 ----
    const int bgCnt = min(scal[0], BGCAP);
    {
        const int nStage = min(totEv, EVcap);
        float2 sc[4]; unsigned short sp[4];
        #pragma unroll
        for (int k = 0; k < 4; k++) {
            int i = t + (k << 10);
            if (i < nStage) { int slot = evPool[i]; sp[k] = ldsEnt[slot]; sc[k] = bucketC[slot]; }
        }
        __syncthreads();
        #pragma unroll
        for (int k = 0; k < 4; k++) {
            int i = t + (k << 10);
            if (i < nStage) { ldsEnt[nBg0 + i] = sp[k]; bucketC[nBg0 + i] = sc[k]; }
        }
        if (t < bgCnt) vSteps[t] = ((const float2*)Vb)[bgListSh[t]];   // evPool dead
    }
    __syncthreads();

    // ---- beta: speculative argmins — 5 steps per wave share one stream ----
    for (int s0 = wv; s0 < bgCnt; s0 += 80) {
        u64 best[5]; float vxq[5], vyq[5]; int limq[5];
        int maxLim = 0;
        #pragma unroll
        for (int q = 0; q < 5; q++) {
            int s = s0 + 16 * q;
            best[q] = ~0ull; limq[q] = 0; vxq[q] = 0.0f; vyq[q] = 0.0f;
            if (s < bgCnt) {
                int js = bgListSh[s];
                float2 v = vSteps[s];
                vxq[q] = v.x; vyq[q] = v.y;
                limq[q] = nBg0 + min((int)evAx[js], EVcap);
                maxLim = max(maxLim, limq[q]);
            }
        }
        for (int i = lane; i < maxLim; i += 64) {
            float2 c = bucketC[i];
            unsigned p = ldsEnt[i];
            #pragma unroll
            for (int q = 0; q < 5; q++) {
                if (i < limq[q]) {
                    float d = pdist(vxq[q], vyq[q], c.x, c.y);
                    u64 pk = ((u64)__float_as_uint(d) << 32) | p;
                    if (pk < best[q]) best[q] = pk;
                }
            }
        }
        #pragma unroll
        for (int q = 0; q < 5; q++) {
            int s = s0 + 16 * q;
            if (s < bgCnt) {
                int js = bgListSh[s];
                int ne = evAx[js];
                u64 bq = best[q];
                for (int ei = EVcap + lane; ei < ne; ei += 64) {    // spill tail (rare)
                    if (ei - EVcap >= spillCap) break;
                    unsigned p = evSpillB[ei - EVcap];
                    float2 c = Ub2[p];
                    float d = pdist(vxq[q], vyq[q], c.x, c.y);
                    u64 pk = ((u64)__float_as_uint(d) << 32) | p;
                    if (pk < bq) bq = pk;
                }
                #pragma unroll
                for (int off = 32; off >= 1; off >>= 1) {
                    u64 o = __shfl_xor(bq, off, 64);
                    if (o < bq) bq = o;
                }
                if (lane == 0) specWin[s] = bq;       // bEnd/occA dead -> alias
            }
        }
    }
    __syncthreads();

    // ---- 2c: duplicate-winner check; parallel commit or sequential walk ----
    if (t < bgCnt) {
        u64 w0 = specWin[t];
        if (w0 != ~0ull) {
            unsigned myp = (unsigned)(w0 & 0xFFFFFFFFull);
            for (int s2 = 0; s2 < t; s2++) {
                u64 ws = specWin[s2];
                if (ws != ~0ull && (unsigned)(ws & 0xFFFFFFFFull) == myp) { scal[2] = 1; break; }
            }
        }
    }
    __syncthreads();
    float bgCost = 0.0f;
    if (scal[2] == 0) {
        // all winners distinct -> every speculative winner exact
        if (t < bgCnt) {
            int js = bgListSh[t];
            u64 w0 = specWin[t];
            if (w0 == ~0ull) matchU[js] = -1;
            else {
                matchU[js] = (short)(w0 & 0xFFFFFFFFull);
                costPartial = __fadd_rn(costPartial, __uint_as_float((unsigned)(w0 >> 32)));
            }
        }
    } else if (t < 64) {
        // sequential walk: apply events, O(1) validity check, rare recompute
        int applied = 0;
        for (int s = 0; s < bgCnt; s++) {
            int js = bgListSh[s];
            int target = evAx[js];
            for (int base = applied; base < target; base += 64) {
                int idx = base + t;
                if (idx < target) {
                    int p = (idx < EVcap) ? (int)ldsEnt[nBg0 + idx]
                                          : (int)evSpillB[idx - EVcap];
                    atomicOr(&bgbits[p >> 5], 1u << (p & 31));
                }
            }
            applied = target;
            __threadfence_block();
            u64 w0 = specWin[s];
            if (w0 == ~0ull) {
                if (t == 0) matchU[js] = -1;
            } else {
                int u = (int)(w0 & 0xFFFFFFFFull);
                bool setb = (bgbits[u >> 5] >> (u & 31)) & 1u;
                if (setb) {
                    if (t == 0) {
                        matchU[js] = (short)u;
                        atomicAnd(&bgbits[u >> 5], ~(1u << (u & 31)));
                        bgCost = __fadd_rn(bgCost, __uint_as_float((unsigned)(w0 >> 32)));
                    }
                } else {
                    float2 v = vSteps[s];
                    u64 best = ~0ull;
                    #pragma unroll
                    for (int i = 0; i < 2; i++) {
                        int wi = t * 2 + i;
                        unsigned bits = bgbits[wi];
                        int pb = wi << 5;
                        while (bits) {
                            int bpos = __builtin_ctz(bits);
                            bits &= bits - 1;
                            int p = pb + bpos;
                            float2 uu = Ub2[p];
                            float d = pdist(v.x, v.y, uu.x, uu.y);
                            u64 pk = ((u64)__float_as_uint(d) << 32) | (unsigned)p;
                            if (pk < best) best = pk;
                        }
                    }
                    #pragma unroll
                    for (int off = 32; off >= 1; off >>= 1) {
                        u64 o = __shfl_xor(best, off, 64);
                        if (o < best) best = o;
                    }
                    if (t == 0) {
                        if (best != ~0ull) {
                            int u2 = (int)(best & 0xFFFFFFFFull);
                            matchU[js] = (short)u2;
                            atomicAnd(&bgbits[u2 >> 5], ~(1u << (u2 & 31)));
                            bgCost = __fadd_rn(bgCost, __uint_as_float((unsigned)(best >> 32)));
                        } else matchU[js] = -1;
                    }
                }
                __threadfence_block();
            }
        }
    }
    __syncthreads();

    // ---- epilogue: cost reduction + outputs ----
    {
        float cp = costPartial;
        #pragma unroll
        for (int off = 32; off >= 1; off >>= 1) cp += __shfl_xor(cp, off, 64);
        if (lane == 0) wScrF[wv] = cp;
    }
    __syncthreads();
    if (t == 0) {
        float tot = bgCost;
        for (int i = 0; i < 16; ++i) tot = __fadd_rn(tot, wScrF[i]);
        out[(size_t)2 * B * NGT + b] = tot;
    }
    {
        int u = matchU[t];
        out[(size_t)b * NGT + t] = (float)u;
        out[(size_t)B * NGT + (size_t)b * NGT + t] = (u >= 0) ? (float)t : -1.0f;
    }
}

extern "C" void kernel_launch(void* const* d_in, const int* in_sizes, int n_in,
                              void* d_out, int out_size, void* d_ws, size_t ws_size,
                              hipStream_t stream) {
    const float* pred   = (const float*)d_in[0];
    const float* coords = (const float*)d_in[1];
    const int*   keys   = (const int*)d_in[2];
    const int*   masks  = (const int*)d_in[3];
    float* out = (float*)d_out;
    int B = in_sizes[2] / NGT;   // 8
    int useWs = (B == 8 && ws_size >= (size_t)WS_NEED) ? 1 : 0;
    unsigned short* partP  = (unsigned short*)d_ws;
    unsigned short* labsP  = (unsigned short*)((char*)d_ws + LAB_OFF);
    unsigned short* spillP = (unsigned short*)((char*)d_ws + SPILL_OFF);
    if (useWs) {
        label_kernel<<<B * 8, 512, 0, stream>>>(pred, masks, partP, labsP);
    }
    matcher_kernel<<<B, 1024, 0, stream>>>(pred, coords, keys, masks, out,
                                           partP, labsP, spillP, useWs, B);
}